// Round 7
// baseline (4005.006 us; speedup 1.0000x reference)
//
#include <hip/hip_runtime.h>

#define NV_N 400
#define NN   160000
#define EPSV 1e-4f
#define IND_BASE ((size_t)160400 * 64)
#define REP  64   // DIAGNOSTIC: idempotent repeat to surface per-kernel durations in rocprof

// ws offsets in floats
#define OFF_A    0         // 160000  A matrix (flat e = i*400+j)
#define OFF_P2   160000    // 12800
#define OFF_Q2   172800    // 12800
#define OFF_R    185600    // 25600
#define OFF_S    211200    // 25600
#define OFF_V4   236800    // 25600
#define OFF_AR   262400    // 25600  alpha_raw
#define OFF_NV   288000    // 400    norm_value
#define OFF_DV   288400    // 400    1/sqrt(deg)
#define OFF_GMAX 288800    // 1 (uint bits of max|alpha_raw|)
#define OFF_CNT  288832    // 400 (int) per-row active count
#define OFF_LIST 289280    // up to 160000 (int) compact active-edge list
#define OFF_WV   449280    // cap*64 gamma-weighted embeddings

// kA: per-node precompute. grid 400, block 256.
__global__ __launch_bounds__(256) void kA_pre(
    const float* __restrict__ NEE, const float* __restrict__ NFN,
    const float* __restrict__ W_n2e, const float* __restrict__ b_n2e,
    const float* __restrict__ W_n2e2, const float* __restrict__ b_n2e2,
    const float* __restrict__ W_ev1, const float* __restrict__ b_ev1,
    const float* __restrict__ W4,
    const float* __restrict__ W_ft1, const float* __restrict__ b_ft1,
    const float* __restrict__ W_ft2, const float* __restrict__ b_ft2,
    float* __restrict__ ws)
{
    __shared__ float xne[64], xnf[64], tP[64], tQ[64], hidN[32], hidF[32];
    int i = blockIdx.x, t = threadIdx.x;
    for (int rep = 0; rep < REP; ++rep) {
    __syncthreads();
    if (t < 64) { xne[t] = NEE[i*64+t]; xnf[t] = NFN[i*64+t]; }
    if (i == 0 && t == 0) ((unsigned*)ws)[OFF_GMAX] = 0u;
    __syncthreads();
    if (t < 64) {
        int dd = t;
        float pv = b_n2e[dd], qv = 0.f, rv = b_n2e2[dd], sv = 0.f, v4 = 0.f;
        for (int k = 0; k < 64; ++k) {
            float xk = xne[k];
            pv += xk * W_n2e[k*64+dd];
            qv += xk * W_n2e[(64+k)*64+dd];
            rv += xk * W_n2e2[k*64+dd];
            sv += xk * W_n2e2[(64+k)*64+dd];
            v4 += fmaxf(xnf[k]-xk, 0.f) * W4[k*64+dd];
        }
        tP[dd] = pv; tQ[dd] = qv;
        ws[OFF_R  + i*64+dd] = rv;
        ws[OFF_S  + i*64+dd] = sv;
        ws[OFF_V4 + i*64+dd] = v4;
    } else if (t >= 64 && t < 96) {
        int dd = t - 64;
        float hn = b_ft1[dd], hf = b_ft1[dd];
        for (int k = 0; k < 64; ++k) { hn += xne[k]*W_ft1[k*32+dd]; hf += xnf[k]*W_ft1[k*32+dd]; }
        hidN[dd] = fmaxf(hn, 0.f); hidF[dd] = fmaxf(hf, 0.f);
    }
    __syncthreads();
    if (t < 32) {
        float p2 = b_ev1[t], q2 = 0.f;
        for (int c = 0; c < 64; ++c) { p2 += tP[c]*W_ev1[c*32+t]; q2 += tQ[c]*W_ev1[c*32+t]; }
        ws[OFF_P2 + i*32+t] = p2;
        ws[OFF_Q2 + i*32+t] = q2;
    }
    if (t == 96) {
        float num = b_ft2[0], den = b_ft2[0];
        for (int c = 0; c < 32; ++c) { num += hidN[c]*W_ft2[c]; den += hidF[c]*W_ft2[c]; }
        float dv = (den == 0.f) ? EPSV : den;
        ws[OFF_NV + i] = num / dv;
    }
    }
}

// K2: A row + degree + count + indicator + owner-computes pred_edge.
// grid 400 (row i), block 256.
__global__ __launch_bounds__(256) void k2_row(
    const float* __restrict__ NEE,
    const float* __restrict__ W_ev2, const float* __restrict__ b_ev2,
    const float* __restrict__ W_e2e, const float* __restrict__ b_e2e,
    float* __restrict__ ws, float* __restrict__ out)
{
    __shared__ float p2s[32], wev2[32], redf[256];
    __shared__ int rcnt[256];
    __shared__ unsigned char flag[NV_N];
    __shared__ int act[NV_N];
    __shared__ int s_cnt;
    int i = blockIdx.x, t = threadIdx.x;
    for (int rep = 0; rep < REP; ++rep) {
    __syncthreads();
    if (t < 32) { p2s[t] = ws[OFF_P2 + i*32+t]; wev2[t] = W_ev2[t]; }
    __syncthreads();
    float b2 = b_ev2[0];
    float s = 0.f; int cc = 0;
    for (int j = t; j < NV_N; j += 256) {
        const float4* q2row = (const float4*)&ws[OFF_Q2 + j*32];
        float v = b2;
        #pragma unroll
        for (int c4 = 0; c4 < 8; ++c4) {
            float4 q = q2row[c4];
            v += fmaxf(p2s[c4*4+0]+q.x, 0.f) * wev2[c4*4+0];
            v += fmaxf(p2s[c4*4+1]+q.y, 0.f) * wev2[c4*4+1];
            v += fmaxf(p2s[c4*4+2]+q.z, 0.f) * wev2[c4*4+2];
            v += fmaxf(p2s[c4*4+3]+q.w, 0.f) * wev2[c4*4+3];
        }
        float a = fmaxf(v, 0.f);
        ws[OFF_A + i*NV_N + j] = a;
        bool f = (a >= 1.0f);
        flag[j] = f ? 1 : 0;
        out[IND_BASE + (size_t)i*NV_N + j] = f ? 1.f : 0.f;
        s += a; cc += f ? 1 : 0;
    }
    redf[t] = s; rcnt[t] = cc;
    __syncthreads();
    for (int st = 128; st > 0; st >>= 1) {
        if (t < st) { redf[t] += redf[t+st]; rcnt[t] += rcnt[t+st]; }
        __syncthreads();
    }
    if (t == 0) {
        ws[OFF_DV + i] = rsqrtf(fmaxf(redf[0], EPSV));
        ((int*)ws)[OFF_CNT + i] = rcnt[0];
    }
    if (t < 64) {
        int base = 0;
        for (int ch = 0; ch < 7; ++ch) {
            int j = ch*64 + t;
            bool f = (j < NV_N) && (flag[j] != 0);
            unsigned long long m = __ballot(f);
            if (f) {
                int pre = __popcll(m & ((1ull << t) - 1ull));
                act[base + pre] = j;
            }
            base += __popcll(m);
        }
        if (t == 0) s_cnt = base;
    }
    __syncthreads();
    {
        const float4 z4 = make_float4(0.f, 0.f, 0.f, 0.f);
        float4* orow = (float4*)(out + (NV_N + (size_t)i*NV_N) * 64);
        for (int q = t; q < NV_N*16; q += 256) {
            if (!flag[q >> 4]) orow[q] = z4;
        }
    }
    int cnt = s_cnt, lane = t & 63, w = t >> 6;
    for (int k = w; k < cnt; k += 4) {
        int j = act[k];
        int e = i*NV_N + j;
        float emb = NEE[(size_t)(NV_N + e)*64 + lane];
        float v = b_e2e[lane] + ws[OFF_R + i*64 + lane] + ws[OFF_S + j*64 + lane];
        #pragma unroll
        for (int c = 0; c < 64; ++c) v += __shfl(emb, c) * W_e2e[c*64 + lane];
        out[(size_t)(NV_N + e)*64 + lane] = v;
    }
    }
}

// K3: alpha chain + global compaction + wv per active edge. grid 400, block 256.
__global__ __launch_bounds__(256) void k3_alpha_compact(
    const float* __restrict__ NEE,
    const float* __restrict__ W3,
    const float* __restrict__ W_alpha, const float* __restrict__ b_alpha,
    const float* __restrict__ W_gamma, const float* __restrict__ b_gamma,
    float* __restrict__ ws, int cap)
{
    __shared__ float part[4][64];
    __shared__ int red[256];
    __shared__ int s_off;
    int i = blockIdx.x, t = threadIdx.x, lane = t & 63, w = t >> 6;
    for (int rep = 0; rep < REP; ++rep) {
    __syncthreads();
    int os = 0;
    for (int r = t; r < i; r += 256) os += ((const int*)ws)[OFF_CNT + r];
    red[t] = os; __syncthreads();
    for (int st = 128; st > 0; st >>= 1) { if (t < st) red[t] += red[t+st]; __syncthreads(); }
    if (t == 0) s_off = red[0];
    float acc = 0.f;
    for (int j = w*100; j < w*100 + 100; ++j) {
        float coef = ws[OFF_A + i*NV_N + j] * ws[OFF_DV + j];
        acc += coef * NEE[j*64 + lane];
    }
    part[w][lane] = acc;
    __syncthreads();
    if (w == 0) {
        float nm = (part[0][lane] + part[1][lane] + part[2][lane] + part[3][lane]) * ws[OFF_DV + i];
        float mc = 0.f;
        #pragma unroll
        for (int c = 0; c < 64; ++c) mc += __shfl(nm, c) * W3[c*64 + lane];
        float ar = b_alpha[lane];
        #pragma unroll
        for (int c = 0; c < 64; ++c) ar += __shfl(mc, c) * W_alpha[c*64 + lane];
        ws[OFF_AR + i*64 + lane] = ar;
        float mx = fabsf(ar);
        #pragma unroll
        for (int off = 32; off > 0; off >>= 1) mx = fmaxf(mx, __shfl_xor(mx, off));
        if (lane == 0) atomicMax((unsigned*)ws + OFF_GMAX, __float_as_uint(mx));
    } else if (w == 1) {
        int base = 0;
        for (int ch = 0; ch < 7; ++ch) {
            int j = ch*64 + lane;
            float a = (j < NV_N) ? ws[OFF_A + i*NV_N + j] : 0.f;
            bool f = (a >= 1.0f);
            unsigned long long m = __ballot(f);
            if (f) {
                int pre = __popcll(m & ((1ull << lane) - 1ull));
                int slot = s_off + base + pre;
                if (slot < cap) ((int*)ws)[OFF_LIST + slot] = i*NV_N + j;
            }
            base += __popcll(m);
        }
    }
    __syncthreads();
    int cnt = ((const int*)ws)[OFF_CNT + i];
    for (int k = w; k < cnt; k += 4) {
        int slot = s_off + k;
        if (slot >= cap) break;
        int e = ((const int*)ws)[OFF_LIST + slot];
        float emb = NEE[(size_t)(NV_N + e)*64 + lane];
        float g = b_gamma[lane];
        #pragma unroll
        for (int c = 0; c < 64; ++c) g += __shfl(emb, c) * W_gamma[c*64 + lane];
        float mx = g;
        #pragma unroll
        for (int off = 32; off > 0; off >>= 1) mx = fmaxf(mx, __shfl_xor(mx, off));
        float p = __expf(g - mx);
        float ssum = p;
        #pragma unroll
        for (int off = 32; off > 0; off >>= 1) ssum += __shfl_xor(ssum, off);
        ws[OFF_WV + (size_t)slot*64 + lane] = (p / ssum) * emb;
    }
    }
}

// K4: gather-GEMM over compact list + final node out. grid 400, block 256.
#define LCHUNK 4096
__global__ __launch_bounds__(256) void k4_final(
    const float* __restrict__ A_ne,
    const float* __restrict__ ws, int cap,
    float* __restrict__ out)
{
    __shared__ float av[LCHUNK];
    __shared__ float part[4][64];
    __shared__ int red[256];
    int i = blockIdx.x, t = threadIdx.x, lane = t & 63, w = t >> 6;
    for (int rep = 0; rep < REP; ++rep) {
    __syncthreads();
    int os = 0;
    for (int r = t; r < NV_N; r += 256) os += ((const int*)ws)[OFF_CNT + r];
    red[t] = os; __syncthreads();
    for (int st = 128; st > 0; st >>= 1) { if (t < st) red[t] += red[t+st]; __syncthreads(); }
    int nnz = red[0]; if (nnz > cap) nnz = cap;
    const float* Arow = A_ne + (size_t)i * NN;
    float acc = 0.f;
    for (int base = 0; base < nnz; base += LCHUNK) {
        int m = nnz - base; if (m > LCHUNK) m = LCHUNK;
        __syncthreads();
        for (int l = t; l < m; l += 256) {
            int e = ((const int*)ws)[OFF_LIST + base + l];
            av[l] = Arow[e];
        }
        __syncthreads();
        for (int l = w; l < m; l += 4)
            acc = fmaf(av[l], ws[OFF_WV + (size_t)(base + l)*64 + lane], acc);
    }
    part[w][lane] = acc;
    __syncthreads();
    if (w == 0) {
        float aggr = part[0][lane] + part[1][lane] + part[2][lane] + part[3][lane];
        float amax = fmaxf(__uint_as_float(((const unsigned*)ws)[OFF_GMAX]), EPSV);
        float v = (ws[OFF_AR + i*64 + lane] / amax) * ws[OFF_NV + i] * ws[OFF_V4 + i*64 + lane];
        out[i*64 + lane] = v + aggr;
    }
    }
}

extern "C" void kernel_launch(void* const* d_in, const int* in_sizes, int n_in,
                              void* d_out, int out_size, void* d_ws, size_t ws_size,
                              hipStream_t stream) {
    const float* NEE     = (const float*)d_in[1];
    const float* NFN     = (const float*)d_in[2];
    const float* A_ne    = (const float*)d_in[3];
    const float* W_alpha = (const float*)d_in[5];
    const float* b_alpha = (const float*)d_in[6];
    const float* W_gamma = (const float*)d_in[7];
    const float* b_gamma = (const float*)d_in[8];
    const float* W_n2e   = (const float*)d_in[9];
    const float* b_n2e   = (const float*)d_in[10];
    const float* W_ev1   = (const float*)d_in[11];
    const float* b_ev1   = (const float*)d_in[12];
    const float* W_ev2   = (const float*)d_in[13];
    const float* b_ev2   = (const float*)d_in[14];
    const float* W_ft1   = (const float*)d_in[15];
    const float* b_ft1   = (const float*)d_in[16];
    const float* W_ft2   = (const float*)d_in[17];
    const float* b_ft2   = (const float*)d_in[18];
    const float* W3      = (const float*)d_in[19];
    const float* W4      = (const float*)d_in[20];
    const float* W_e2e   = (const float*)d_in[21];
    const float* b_e2e   = (const float*)d_in[22];
    const float* W_n2e2  = (const float*)d_in[23];
    const float* b_n2e2  = (const float*)d_in[24];
    float* out = (float*)d_out;
    float* ws  = (float*)d_ws;

    long long cap_ll = ((long long)(ws_size / 4) - OFF_WV) / 64;
    int cap = (cap_ll > NN) ? NN : (cap_ll < 0 ? 0 : (int)cap_ll);

    hipLaunchKernelGGL(kA_pre, dim3(NV_N), dim3(256), 0, stream,
        NEE, NFN, W_n2e, b_n2e, W_n2e2, b_n2e2, W_ev1, b_ev1, W4,
        W_ft1, b_ft1, W_ft2, b_ft2, ws);
    hipLaunchKernelGGL(k2_row, dim3(NV_N), dim3(256), 0, stream,
        NEE, W_ev2, b_ev2, W_e2e, b_e2e, ws, out);
    hipLaunchKernelGGL(k3_alpha_compact, dim3(NV_N), dim3(256), 0, stream,
        NEE, W3, W_alpha, b_alpha, W_gamma, b_gamma, ws, cap);
    hipLaunchKernelGGL(k4_final, dim3(NV_N), dim3(256), 0, stream,
        A_ne, ws, cap, out);
}

// Round 8
// 60.306 us; speedup vs baseline: 66.4115x; 66.4115x over previous
//
#include <hip/hip_runtime.h>

#define NV_N 400
#define NN   160000
#define EPSV 1e-4f
#define IND_BASE ((size_t)160400 * 64)

// ws offsets in floats
#define OFF_A    0         // 160000  A matrix (flat e = i*400+j)
#define OFF_P2   160000    // 12800
#define OFF_Q2   172800    // 12800
#define OFF_R    185600    // 25600
#define OFF_S    211200    // 25600
#define OFF_V4   236800    // 25600
#define OFF_AR   262400    // 25600  alpha_raw
#define OFF_NV   288000    // 400    norm_value
#define OFF_DV   288400    // 400    1/sqrt(deg)
#define OFF_GMAX 288800    // 1 (uint bits of max|alpha_raw|)
#define OFF_CNT  288832    // 400 (int) per-row active count
#define OFF_W34  289280    // 4096   W3 @ W_alpha (64x64)
#define OFF_LIST 293376    // up to 160000 (int) compact active-edge list
#define OFF_WV   453376    // cap*64 gamma-weighted embeddings

// kA: per-node precompute (blocks 0..399) + W34 = W3@W_alpha (block 400).
__global__ __launch_bounds__(256) void kA_pre(
    const float* __restrict__ NEE, const float* __restrict__ NFN,
    const float* __restrict__ W_n2e, const float* __restrict__ b_n2e,
    const float* __restrict__ W_n2e2, const float* __restrict__ b_n2e2,
    const float* __restrict__ W_ev1, const float* __restrict__ b_ev1,
    const float* __restrict__ W4,
    const float* __restrict__ W_ft1, const float* __restrict__ b_ft1,
    const float* __restrict__ W_ft2, const float* __restrict__ b_ft2,
    const float* __restrict__ W3, const float* __restrict__ W_alpha,
    float* __restrict__ ws)
{
    __shared__ float xne[64], xnf[64], tP[64], tQ[64], hidN[32], hidF[32];
    int b = blockIdx.x, t = threadIdx.x;
    if (b == NV_N) {
        // W34[c][d] = sum_k W3[c][k] * W_alpha[k][d]
        int lane = t & 63, w = t >> 6;
        for (int c = w; c < 64; c += 4) {
            float p = 0.f;
            #pragma unroll 8
            for (int k = 0; k < 64; ++k) p += W3[c*64+k] * W_alpha[k*64+lane];
            ws[OFF_W34 + c*64 + lane] = p;
        }
        return;
    }
    int i = b;
    if (t < 64) { xne[t] = NEE[i*64+t]; xnf[t] = NFN[i*64+t]; }
    if (i == 0 && t == 0) ((unsigned*)ws)[OFF_GMAX] = 0u;
    __syncthreads();
    if (t < 64) {
        int dd = t;
        float pv = b_n2e[dd], qv = 0.f, rv = b_n2e2[dd], sv = 0.f, v4 = 0.f;
        for (int k = 0; k < 64; ++k) {
            float xk = xne[k];
            pv += xk * W_n2e[k*64+dd];
            qv += xk * W_n2e[(64+k)*64+dd];
            rv += xk * W_n2e2[k*64+dd];
            sv += xk * W_n2e2[(64+k)*64+dd];
            v4 += fmaxf(xnf[k]-xk, 0.f) * W4[k*64+dd];
        }
        tP[dd] = pv; tQ[dd] = qv;
        ws[OFF_R  + i*64+dd] = rv;
        ws[OFF_S  + i*64+dd] = sv;
        ws[OFF_V4 + i*64+dd] = v4;
    } else if (t >= 64 && t < 96) {
        int dd = t - 64;
        float hn = b_ft1[dd], hf = b_ft1[dd];
        for (int k = 0; k < 64; ++k) { hn += xne[k]*W_ft1[k*32+dd]; hf += xnf[k]*W_ft1[k*32+dd]; }
        hidN[dd] = fmaxf(hn, 0.f); hidF[dd] = fmaxf(hf, 0.f);
    }
    __syncthreads();
    if (t < 32) {
        float p2 = b_ev1[t], q2 = 0.f;
        for (int c = 0; c < 64; ++c) { p2 += tP[c]*W_ev1[c*32+t]; q2 += tQ[c]*W_ev1[c*32+t]; }
        ws[OFF_P2 + i*32+t] = p2;
        ws[OFF_Q2 + i*32+t] = q2;
    }
    if (t == 96) {
        float num = b_ft2[0], den = b_ft2[0];
        for (int c = 0; c < 32; ++c) { num += hidN[c]*W_ft2[c]; den += hidF[c]*W_ft2[c]; }
        float dv = (den == 0.f) ? EPSV : den;
        ws[OFF_NV + i] = num / dv;
    }
}

// K2: A row + degree + count + indicator + owner-computes pred_edge.
// grid 400 (row i), block 256.  (unchanged from R6)
__global__ __launch_bounds__(256) void k2_row(
    const float* __restrict__ NEE,
    const float* __restrict__ W_ev2, const float* __restrict__ b_ev2,
    const float* __restrict__ W_e2e, const float* __restrict__ b_e2e,
    float* __restrict__ ws, float* __restrict__ out)
{
    __shared__ float p2s[32], wev2[32], redf[256];
    __shared__ int rcnt[256];
    __shared__ unsigned char flag[NV_N];
    __shared__ int act[NV_N];
    __shared__ int s_cnt;
    int i = blockIdx.x, t = threadIdx.x;
    if (t < 32) { p2s[t] = ws[OFF_P2 + i*32+t]; wev2[t] = W_ev2[t]; }
    __syncthreads();
    float b2 = b_ev2[0];
    float s = 0.f; int cc = 0;
    for (int j = t; j < NV_N; j += 256) {
        const float4* q2row = (const float4*)&ws[OFF_Q2 + j*32];
        float v = b2;
        #pragma unroll
        for (int c4 = 0; c4 < 8; ++c4) {
            float4 q = q2row[c4];
            v += fmaxf(p2s[c4*4+0]+q.x, 0.f) * wev2[c4*4+0];
            v += fmaxf(p2s[c4*4+1]+q.y, 0.f) * wev2[c4*4+1];
            v += fmaxf(p2s[c4*4+2]+q.z, 0.f) * wev2[c4*4+2];
            v += fmaxf(p2s[c4*4+3]+q.w, 0.f) * wev2[c4*4+3];
        }
        float a = fmaxf(v, 0.f);
        ws[OFF_A + i*NV_N + j] = a;
        bool f = (a >= 1.0f);
        flag[j] = f ? 1 : 0;
        out[IND_BASE + (size_t)i*NV_N + j] = f ? 1.f : 0.f;
        s += a; cc += f ? 1 : 0;
    }
    redf[t] = s; rcnt[t] = cc;
    __syncthreads();
    for (int st = 128; st > 0; st >>= 1) {
        if (t < st) { redf[t] += redf[t+st]; rcnt[t] += rcnt[t+st]; }
        __syncthreads();
    }
    if (t == 0) {
        ws[OFF_DV + i] = rsqrtf(fmaxf(redf[0], EPSV));
        ((int*)ws)[OFF_CNT + i] = rcnt[0];
    }
    if (t < 64) {
        int base = 0;
        for (int ch = 0; ch < 7; ++ch) {
            int j = ch*64 + t;
            bool f = (j < NV_N) && (flag[j] != 0);
            unsigned long long m = __ballot(f);
            if (f) {
                int pre = __popcll(m & ((1ull << t) - 1ull));
                act[base + pre] = j;
            }
            base += __popcll(m);
        }
        if (t == 0) s_cnt = base;
    }
    __syncthreads();
    {
        const float4 z4 = make_float4(0.f, 0.f, 0.f, 0.f);
        float4* orow = (float4*)(out + (NV_N + (size_t)i*NV_N) * 64);
        for (int q = t; q < NV_N*16; q += 256) {
            if (!flag[q >> 4]) orow[q] = z4;
        }
    }
    int cnt = s_cnt, lane = t & 63, w = t >> 6;
    for (int k = w; k < cnt; k += 4) {
        int j = act[k];
        int e = i*NV_N + j;
        float emb = NEE[(size_t)(NV_N + e)*64 + lane];
        float v = b_e2e[lane] + ws[OFF_R + i*64 + lane] + ws[OFF_S + j*64 + lane];
        #pragma unroll
        for (int c = 0; c < 64; ++c) v += __shfl(emb, c) * W_e2e[c*64 + lane];
        out[(size_t)(NV_N + e)*64 + lane] = v;
    }
}

// K3 (REWRITTEN): alpha chain via LDS-staged coef + W34, compaction, wv.
// grid 400 (node/row i), block 256.
__global__ __launch_bounds__(256) void k3_alpha_compact(
    const float* __restrict__ NEE,
    const float* __restrict__ b_alpha,
    const float* __restrict__ W_gamma, const float* __restrict__ b_gamma,
    float* __restrict__ ws, int cap)
{
    __shared__ float coef[NV_N];
    __shared__ float part[4][64];
    __shared__ float nmS[64];
    __shared__ int act[NV_N];
    __shared__ int red[256];
    __shared__ int s_off, s_cnt;
    int i = blockIdx.x, t = threadIdx.x, lane = t & 63, w = t >> 6;

    // prefix: offset = sum CNT[r] for r < i
    int os = 0;
    for (int r = t; r < i; r += 256) os += ((const int*)ws)[OFF_CNT + r];
    red[t] = os; __syncthreads();
    for (int st = 128; st > 0; st >>= 1) { if (t < st) red[t] += red[t+st]; __syncthreads(); }
    if (t == 0) s_off = red[0];

    // stage coef[j] = A[i][j]*dv[j] (parallel, coalesced) — kills the serial
    // uniform-load chain that made the old k3 latency-bound
    for (int j = t; j < NV_N; j += 256)
        coef[j] = ws[OFF_A + i*NV_N + j] * ws[OFF_DV + j];
    __syncthreads();   // also publishes s_off

    // nm partials: wave w covers 100 j's; LDS broadcast + coalesced NEE loads
    float acc = 0.f;
    #pragma unroll 4
    for (int j = w*100; j < w*100 + 100; ++j)
        acc += coef[j] * NEE[j*64 + lane];
    part[w][lane] = acc;
    __syncthreads();
    if (t < 64) nmS[t] = (part[0][t] + part[1][t] + part[2][t] + part[3][t]) * ws[OFF_DV + i];
    __syncthreads();

    // ar = b_alpha + nmS @ W34, split 4 ways over c (16 each)
    {
        float p = 0.f;
        #pragma unroll
        for (int c = w*16; c < w*16 + 16; ++c)
            p += nmS[c] * ws[OFF_W34 + c*64 + lane];
        part[w][lane] = p;
    }
    __syncthreads();
    if (w == 0) {
        float ar = b_alpha[lane] + part[0][lane] + part[1][lane] + part[2][lane] + part[3][lane];
        ws[OFF_AR + i*64 + lane] = ar;
        float mx = fabsf(ar);
        #pragma unroll
        for (int off = 32; off > 0; off >>= 1) mx = fmaxf(mx, __shfl_xor(mx, off));
        if (lane == 0) atomicMax((unsigned*)ws + OFF_GMAX, __float_as_uint(mx));
    } else if (w == 1) {
        // ordered compaction: LDS act[] + global LIST
        int base = 0;
        for (int ch = 0; ch < 7; ++ch) {
            int j = ch*64 + lane;
            float a = (j < NV_N) ? ws[OFF_A + i*NV_N + j] : 0.f;
            bool f = (a >= 1.0f);
            unsigned long long m = __ballot(f);
            if (f) {
                int pre = __popcll(m & ((1ull << lane) - 1ull));
                act[base + pre] = j;
                int slot = s_off + base + pre;
                if (slot < cap) ((int*)ws)[OFF_LIST + slot] = i*NV_N + j;
            }
            base += __popcll(m);
        }
        if (lane == 0) s_cnt = base;
    }
    __syncthreads();

    // wv for this row's actives: wave w takes k = w, w+4, ...
    int cnt = s_cnt;
    for (int k = w; k < cnt; k += 4) {
        int slot = s_off + k;
        if (slot >= cap) break;
        int e = i*NV_N + act[k];
        float emb = NEE[(size_t)(NV_N + e)*64 + lane];
        float g = b_gamma[lane];
        #pragma unroll
        for (int c = 0; c < 64; ++c) g += __shfl(emb, c) * W_gamma[c*64 + lane];
        float mx = g;
        #pragma unroll
        for (int off = 32; off > 0; off >>= 1) mx = fmaxf(mx, __shfl_xor(mx, off));
        float p = __expf(g - mx);
        float ssum = p;
        #pragma unroll
        for (int off = 32; off > 0; off >>= 1) ssum += __shfl_xor(ssum, off);
        ws[OFF_WV + (size_t)slot*64 + lane] = (p / ssum) * emb;
    }
}

// K4: gather-GEMM over compact list + final node out. grid 400, block 256.
// (unchanged from R6)
#define LCHUNK 4096
__global__ __launch_bounds__(256) void k4_final(
    const float* __restrict__ A_ne,
    const float* __restrict__ ws, int cap,
    float* __restrict__ out)
{
    __shared__ float av[LCHUNK];
    __shared__ float part[4][64];
    __shared__ int red[256];
    int i = blockIdx.x, t = threadIdx.x, lane = t & 63, w = t >> 6;
    int os = 0;
    for (int r = t; r < NV_N; r += 256) os += ((const int*)ws)[OFF_CNT + r];
    red[t] = os; __syncthreads();
    for (int st = 128; st > 0; st >>= 1) { if (t < st) red[t] += red[t+st]; __syncthreads(); }
    int nnz = red[0]; if (nnz > cap) nnz = cap;
    const float* Arow = A_ne + (size_t)i * NN;
    float acc = 0.f;
    for (int base = 0; base < nnz; base += LCHUNK) {
        int m = nnz - base; if (m > LCHUNK) m = LCHUNK;
        __syncthreads();
        for (int l = t; l < m; l += 256) {
            int e = ((const int*)ws)[OFF_LIST + base + l];
            av[l] = Arow[e];
        }
        __syncthreads();
        for (int l = w; l < m; l += 4)
            acc = fmaf(av[l], ws[OFF_WV + (size_t)(base + l)*64 + lane], acc);
    }
    part[w][lane] = acc;
    __syncthreads();
    if (w == 0) {
        float aggr = part[0][lane] + part[1][lane] + part[2][lane] + part[3][lane];
        float amax = fmaxf(__uint_as_float(((const unsigned*)ws)[OFF_GMAX]), EPSV);
        float v = (ws[OFF_AR + i*64 + lane] / amax) * ws[OFF_NV + i] * ws[OFF_V4 + i*64 + lane];
        out[i*64 + lane] = v + aggr;
    }
}

extern "C" void kernel_launch(void* const* d_in, const int* in_sizes, int n_in,
                              void* d_out, int out_size, void* d_ws, size_t ws_size,
                              hipStream_t stream) {
    const float* NEE     = (const float*)d_in[1];
    const float* NFN     = (const float*)d_in[2];
    const float* A_ne    = (const float*)d_in[3];
    const float* W_alpha = (const float*)d_in[5];
    const float* b_alpha = (const float*)d_in[6];
    const float* W_gamma = (const float*)d_in[7];
    const float* b_gamma = (const float*)d_in[8];
    const float* W_n2e   = (const float*)d_in[9];
    const float* b_n2e   = (const float*)d_in[10];
    const float* W_ev1   = (const float*)d_in[11];
    const float* b_ev1   = (const float*)d_in[12];
    const float* W_ev2   = (const float*)d_in[13];
    const float* b_ev2   = (const float*)d_in[14];
    const float* W_ft1   = (const float*)d_in[15];
    const float* b_ft1   = (const float*)d_in[16];
    const float* W_ft2   = (const float*)d_in[17];
    const float* b_ft2   = (const float*)d_in[18];
    const float* W3      = (const float*)d_in[19];
    const float* W4      = (const float*)d_in[20];
    const float* W_e2e   = (const float*)d_in[21];
    const float* b_e2e   = (const float*)d_in[22];
    const float* W_n2e2  = (const float*)d_in[23];
    const float* b_n2e2  = (const float*)d_in[24];
    float* out = (float*)d_out;
    float* ws  = (float*)d_ws;

    long long cap_ll = ((long long)(ws_size / 4) - OFF_WV) / 64;
    int cap = (cap_ll > NN) ? NN : (cap_ll < 0 ? 0 : (int)cap_ll);

    hipLaunchKernelGGL(kA_pre, dim3(NV_N + 1), dim3(256), 0, stream,
        NEE, NFN, W_n2e, b_n2e, W_n2e2, b_n2e2, W_ev1, b_ev1, W4,
        W_ft1, b_ft1, W_ft2, b_ft2, W3, W_alpha, ws);
    hipLaunchKernelGGL(k2_row, dim3(NV_N), dim3(256), 0, stream,
        NEE, W_ev2, b_ev2, W_e2e, b_e2e, ws, out);
    hipLaunchKernelGGL(k3_alpha_compact, dim3(NV_N), dim3(256), 0, stream,
        NEE, b_alpha, W_gamma, b_gamma, ws, cap);
    hipLaunchKernelGGL(k4_final, dim3(NV_N), dim3(256), 0, stream,
        A_ne, ws, cap, out);
}

// Round 9
// 58.949 us; speedup vs baseline: 67.9406x; 1.0230x over previous
//
#include <hip/hip_runtime.h>

#define NV_N 400
#define NN   160000
#define EPSV 1e-4f
#define IND_BASE ((size_t)160400 * 64)

// ws offsets in floats
#define OFF_A     0         // 160000  A matrix (flat e = i*400+j)
#define OFF_P2    160000    // 12800
#define OFF_Q2    172800    // 12800
#define OFF_R     185600    // 25600
#define OFF_S     211200    // 25600
#define OFF_V4    236800    // 25600
#define OFF_AR    262400    // 25600  alpha_raw
#define OFF_NV    288000    // 400    norm_value
#define OFF_DV    288400    // 400    1/sqrt(deg)
#define OFF_CNT   288832    // 400 (int) per-row active count
#define OFF_W34   289280    // 4096   W3 @ W_alpha (64x64)
#define OFF_ARMAX 293376    // 400    per-row max |alpha_raw|  (replaces atomicMax)
#define OFF_LIST  293888    // up to 160000 (int) compact active-edge list
#define OFF_WV    453888    // cap*64 gamma-weighted embeddings

// kA: per-node precompute (blocks 0..399) + W34 = W3@W_alpha (block 400).
__global__ __launch_bounds__(256) void kA_pre(
    const float* __restrict__ NEE, const float* __restrict__ NFN,
    const float* __restrict__ W_n2e, const float* __restrict__ b_n2e,
    const float* __restrict__ W_n2e2, const float* __restrict__ b_n2e2,
    const float* __restrict__ W_ev1, const float* __restrict__ b_ev1,
    const float* __restrict__ W4,
    const float* __restrict__ W_ft1, const float* __restrict__ b_ft1,
    const float* __restrict__ W_ft2, const float* __restrict__ b_ft2,
    const float* __restrict__ W3, const float* __restrict__ W_alpha,
    float* __restrict__ ws)
{
    __shared__ float xne[64], xnf[64], tP[64], tQ[64], hidN[32], hidF[32];
    int b = blockIdx.x, t = threadIdx.x;
    if (b == NV_N) {
        // W34[c][d] = sum_k W3[c][k] * W_alpha[k][d]
        int lane = t & 63, w = t >> 6;
        for (int c = w; c < 64; c += 4) {
            float p = 0.f;
            #pragma unroll 8
            for (int k = 0; k < 64; ++k) p += W3[c*64+k] * W_alpha[k*64+lane];
            ws[OFF_W34 + c*64 + lane] = p;
        }
        return;
    }
    int i = b;
    if (t < 64) { xne[t] = NEE[i*64+t]; xnf[t] = NFN[i*64+t]; }
    __syncthreads();
    if (t < 64) {
        int dd = t;
        float pv = b_n2e[dd], qv = 0.f, rv = b_n2e2[dd], sv = 0.f, v4 = 0.f;
        for (int k = 0; k < 64; ++k) {
            float xk = xne[k];
            pv += xk * W_n2e[k*64+dd];
            qv += xk * W_n2e[(64+k)*64+dd];
            rv += xk * W_n2e2[k*64+dd];
            sv += xk * W_n2e2[(64+k)*64+dd];
            v4 += fmaxf(xnf[k]-xk, 0.f) * W4[k*64+dd];
        }
        tP[dd] = pv; tQ[dd] = qv;
        ws[OFF_R  + i*64+dd] = rv;
        ws[OFF_S  + i*64+dd] = sv;
        ws[OFF_V4 + i*64+dd] = v4;
    } else if (t >= 64 && t < 96) {
        int dd = t - 64;
        float hn = b_ft1[dd], hf = b_ft1[dd];
        for (int k = 0; k < 64; ++k) { hn += xne[k]*W_ft1[k*32+dd]; hf += xnf[k]*W_ft1[k*32+dd]; }
        hidN[dd] = fmaxf(hn, 0.f); hidF[dd] = fmaxf(hf, 0.f);
    }
    __syncthreads();
    if (t < 32) {
        float p2 = b_ev1[t], q2 = 0.f;
        for (int c = 0; c < 64; ++c) { p2 += tP[c]*W_ev1[c*32+t]; q2 += tQ[c]*W_ev1[c*32+t]; }
        ws[OFF_P2 + i*32+t] = p2;
        ws[OFF_Q2 + i*32+t] = q2;
    }
    if (t == 96) {
        float num = b_ft2[0], den = b_ft2[0];
        for (int c = 0; c < 32; ++c) { num += hidN[c]*W_ft2[c]; den += hidF[c]*W_ft2[c]; }
        float dv = (den == 0.f) ? EPSV : den;
        ws[OFF_NV + i] = num / dv;
    }
}

// K2: A row + degree + count + indicator + owner-computes pred_edge.
// grid 400 (row i), block 256.  (unchanged)
__global__ __launch_bounds__(256) void k2_row(
    const float* __restrict__ NEE,
    const float* __restrict__ W_ev2, const float* __restrict__ b_ev2,
    const float* __restrict__ W_e2e, const float* __restrict__ b_e2e,
    float* __restrict__ ws, float* __restrict__ out)
{
    __shared__ float p2s[32], wev2[32], redf[256];
    __shared__ int rcnt[256];
    __shared__ unsigned char flag[NV_N];
    __shared__ int act[NV_N];
    __shared__ int s_cnt;
    int i = blockIdx.x, t = threadIdx.x;
    if (t < 32) { p2s[t] = ws[OFF_P2 + i*32+t]; wev2[t] = W_ev2[t]; }
    __syncthreads();
    float b2 = b_ev2[0];
    float s = 0.f; int cc = 0;
    for (int j = t; j < NV_N; j += 256) {
        const float4* q2row = (const float4*)&ws[OFF_Q2 + j*32];
        float v = b2;
        #pragma unroll
        for (int c4 = 0; c4 < 8; ++c4) {
            float4 q = q2row[c4];
            v += fmaxf(p2s[c4*4+0]+q.x, 0.f) * wev2[c4*4+0];
            v += fmaxf(p2s[c4*4+1]+q.y, 0.f) * wev2[c4*4+1];
            v += fmaxf(p2s[c4*4+2]+q.z, 0.f) * wev2[c4*4+2];
            v += fmaxf(p2s[c4*4+3]+q.w, 0.f) * wev2[c4*4+3];
        }
        float a = fmaxf(v, 0.f);
        ws[OFF_A + i*NV_N + j] = a;
        bool f = (a >= 1.0f);
        flag[j] = f ? 1 : 0;
        out[IND_BASE + (size_t)i*NV_N + j] = f ? 1.f : 0.f;
        s += a; cc += f ? 1 : 0;
    }
    redf[t] = s; rcnt[t] = cc;
    __syncthreads();
    for (int st = 128; st > 0; st >>= 1) {
        if (t < st) { redf[t] += redf[t+st]; rcnt[t] += rcnt[t+st]; }
        __syncthreads();
    }
    if (t == 0) {
        ws[OFF_DV + i] = rsqrtf(fmaxf(redf[0], EPSV));
        ((int*)ws)[OFF_CNT + i] = rcnt[0];
    }
    if (t < 64) {
        int base = 0;
        for (int ch = 0; ch < 7; ++ch) {
            int j = ch*64 + t;
            bool f = (j < NV_N) && (flag[j] != 0);
            unsigned long long m = __ballot(f);
            if (f) {
                int pre = __popcll(m & ((1ull << t) - 1ull));
                act[base + pre] = j;
            }
            base += __popcll(m);
        }
        if (t == 0) s_cnt = base;
    }
    __syncthreads();
    {
        const float4 z4 = make_float4(0.f, 0.f, 0.f, 0.f);
        float4* orow = (float4*)(out + (NV_N + (size_t)i*NV_N) * 64);
        for (int q = t; q < NV_N*16; q += 256) {
            if (!flag[q >> 4]) orow[q] = z4;
        }
    }
    int cnt = s_cnt, lane = t & 63, w = t >> 6;
    for (int k = w; k < cnt; k += 4) {
        int j = act[k];
        int e = i*NV_N + j;
        float emb = NEE[(size_t)(NV_N + e)*64 + lane];
        float v = b_e2e[lane] + ws[OFF_R + i*64 + lane] + ws[OFF_S + j*64 + lane];
        #pragma unroll
        for (int c = 0; c < 64; ++c) v += __shfl(emb, c) * W_e2e[c*64 + lane];
        out[(size_t)(NV_N + e)*64 + lane] = v;
    }
}

// K3: alpha chain via LDS-staged coef + W34, compaction, wv.
// Identical to R8 EXCEPT: per-row max stored to ARMAX (no device atomic).
__global__ __launch_bounds__(256) void k3_alpha_compact(
    const float* __restrict__ NEE,
    const float* __restrict__ b_alpha,
    const float* __restrict__ W_gamma, const float* __restrict__ b_gamma,
    float* __restrict__ ws, int cap)
{
    __shared__ float coef[NV_N];
    __shared__ float part[4][64];
    __shared__ float nmS[64];
    __shared__ int act[NV_N];
    __shared__ int red[256];
    __shared__ int s_off, s_cnt;
    int i = blockIdx.x, t = threadIdx.x, lane = t & 63, w = t >> 6;

    // prefix: offset = sum CNT[r] for r < i
    int os = 0;
    for (int r = t; r < i; r += 256) os += ((const int*)ws)[OFF_CNT + r];
    red[t] = os; __syncthreads();
    for (int st = 128; st > 0; st >>= 1) { if (t < st) red[t] += red[t+st]; __syncthreads(); }
    if (t == 0) s_off = red[0];

    // stage coef[j] = A[i][j]*dv[j] (parallel, coalesced)
    for (int j = t; j < NV_N; j += 256)
        coef[j] = ws[OFF_A + i*NV_N + j] * ws[OFF_DV + j];
    __syncthreads();   // also publishes s_off

    // nm partials: wave w covers 100 j's
    float acc = 0.f;
    #pragma unroll 4
    for (int j = w*100; j < w*100 + 100; ++j)
        acc += coef[j] * NEE[j*64 + lane];
    part[w][lane] = acc;
    __syncthreads();
    if (t < 64) nmS[t] = (part[0][t] + part[1][t] + part[2][t] + part[3][t]) * ws[OFF_DV + i];
    __syncthreads();

    // ar = b_alpha + nmS @ W34, split 4 ways over c
    {
        float p = 0.f;
        #pragma unroll
        for (int c = w*16; c < w*16 + 16; ++c)
            p += nmS[c] * ws[OFF_W34 + c*64 + lane];
        part[w][lane] = p;
    }
    __syncthreads();
    if (w == 0) {
        float ar = b_alpha[lane] + part[0][lane] + part[1][lane] + part[2][lane] + part[3][lane];
        ws[OFF_AR + i*64 + lane] = ar;
        float mx = fabsf(ar);
        #pragma unroll
        for (int off = 32; off > 0; off >>= 1) mx = fmaxf(mx, __shfl_xor(mx, off));
        if (lane == 0) ws[OFF_ARMAX + i] = mx;    // plain store — no contended atomic
    } else if (w == 1) {
        // ordered compaction: LDS act[] + global LIST
        int base = 0;
        for (int ch = 0; ch < 7; ++ch) {
            int j = ch*64 + lane;
            float a = (j < NV_N) ? ws[OFF_A + i*NV_N + j] : 0.f;
            bool f = (a >= 1.0f);
            unsigned long long m = __ballot(f);
            if (f) {
                int pre = __popcll(m & ((1ull << lane) - 1ull));
                act[base + pre] = j;
                int slot = s_off + base + pre;
                if (slot < cap) ((int*)ws)[OFF_LIST + slot] = i*NV_N + j;
            }
            base += __popcll(m);
        }
        if (lane == 0) s_cnt = base;
    }
    __syncthreads();

    // wv for this row's actives
    int cnt = s_cnt;
    for (int k = w; k < cnt; k += 4) {
        int slot = s_off + k;
        if (slot >= cap) break;
        int e = i*NV_N + act[k];
        float emb = NEE[(size_t)(NV_N + e)*64 + lane];
        float g = b_gamma[lane];
        #pragma unroll
        for (int c = 0; c < 64; ++c) g += __shfl(emb, c) * W_gamma[c*64 + lane];
        float mx = g;
        #pragma unroll
        for (int off = 32; off > 0; off >>= 1) mx = fmaxf(mx, __shfl_xor(mx, off));
        float p = __expf(g - mx);
        float ssum = p;
        #pragma unroll
        for (int off = 32; off > 0; off >>= 1) ssum += __shfl_xor(ssum, off);
        ws[OFF_WV + (size_t)slot*64 + lane] = (p / ssum) * emb;
    }
}

// K4: gather-GEMM over compact list + global ARMAX reduce + final node out.
// grid 400, block 256.
#define LCHUNK 4096
__global__ __launch_bounds__(256) void k4_final(
    const float* __restrict__ A_ne,
    const float* __restrict__ ws, int cap,
    float* __restrict__ out)
{
    __shared__ float av[LCHUNK];
    __shared__ float part[4][64];
    __shared__ int red[256];
    __shared__ float redm[256];
    int i = blockIdx.x, t = threadIdx.x, lane = t & 63, w = t >> 6;
    int os = 0;
    float m0 = 0.f;
    for (int r = t; r < NV_N; r += 256) {
        os += ((const int*)ws)[OFF_CNT + r];
        m0 = fmaxf(m0, ws[OFF_ARMAX + r]);
    }
    red[t] = os; redm[t] = m0; __syncthreads();
    for (int st = 128; st > 0; st >>= 1) {
        if (t < st) { red[t] += red[t+st]; redm[t] = fmaxf(redm[t], redm[t+st]); }
        __syncthreads();
    }
    int nnz = red[0]; if (nnz > cap) nnz = cap;
    const float* Arow = A_ne + (size_t)i * NN;
    float acc = 0.f;
    for (int base = 0; base < nnz; base += LCHUNK) {
        int m = nnz - base; if (m > LCHUNK) m = LCHUNK;
        __syncthreads();
        for (int l = t; l < m; l += 256) {
            int e = ((const int*)ws)[OFF_LIST + base + l];
            av[l] = Arow[e];
        }
        __syncthreads();
        for (int l = w; l < m; l += 4)
            acc = fmaf(av[l], ws[OFF_WV + (size_t)(base + l)*64 + lane], acc);
    }
    part[w][lane] = acc;
    __syncthreads();
    if (w == 0) {
        float aggr = part[0][lane] + part[1][lane] + part[2][lane] + part[3][lane];
        float amax = fmaxf(redm[0], EPSV);
        float v = (ws[OFF_AR + i*64 + lane] / amax) * ws[OFF_NV + i] * ws[OFF_V4 + i*64 + lane];
        out[i*64 + lane] = v + aggr;
    }
}

extern "C" void kernel_launch(void* const* d_in, const int* in_sizes, int n_in,
                              void* d_out, int out_size, void* d_ws, size_t ws_size,
                              hipStream_t stream) {
    const float* NEE     = (const float*)d_in[1];
    const float* NFN     = (const float*)d_in[2];
    const float* A_ne    = (const float*)d_in[3];
    const float* W_alpha = (const float*)d_in[5];
    const float* b_alpha = (const float*)d_in[6];
    const float* W_gamma = (const float*)d_in[7];
    const float* b_gamma = (const float*)d_in[8];
    const float* W_n2e   = (const float*)d_in[9];
    const float* b_n2e   = (const float*)d_in[10];
    const float* W_ev1   = (const float*)d_in[11];
    const float* b_ev1   = (const float*)d_in[12];
    const float* W_ev2   = (const float*)d_in[13];
    const float* b_ev2   = (const float*)d_in[14];
    const float* W_ft1   = (const float*)d_in[15];
    const float* b_ft1   = (const float*)d_in[16];
    const float* W_ft2   = (const float*)d_in[17];
    const float* b_ft2   = (const float*)d_in[18];
    const float* W3      = (const float*)d_in[19];
    const float* W4      = (const float*)d_in[20];
    const float* W_e2e   = (const float*)d_in[21];
    const float* b_e2e   = (const float*)d_in[22];
    const float* W_n2e2  = (const float*)d_in[23];
    const float* b_n2e2  = (const float*)d_in[24];
    float* out = (float*)d_out;
    float* ws  = (float*)d_ws;

    long long cap_ll = ((long long)(ws_size / 4) - OFF_WV) / 64;
    int cap = (cap_ll > NN) ? NN : (cap_ll < 0 ? 0 : (int)cap_ll);

    hipLaunchKernelGGL(kA_pre, dim3(NV_N + 1), dim3(256), 0, stream,
        NEE, NFN, W_n2e, b_n2e, W_n2e2, b_n2e2, W_ev1, b_ev1, W4,
        W_ft1, b_ft1, W_ft2, b_ft2, W3, W_alpha, ws);
    hipLaunchKernelGGL(k2_row, dim3(NV_N), dim3(256), 0, stream,
        NEE, W_ev2, b_ev2, W_e2e, b_e2e, ws, out);
    hipLaunchKernelGGL(k3_alpha_compact, dim3(NV_N), dim3(256), 0, stream,
        NEE, b_alpha, W_gamma, b_gamma, ws, cap);
    hipLaunchKernelGGL(k4_final, dim3(NV_N), dim3(256), 0, stream,
        A_ne, ws, cap, out);
}

// Round 10
// 58.613 us; speedup vs baseline: 68.3294x; 1.0057x over previous
//
#include <hip/hip_runtime.h>

#define NV_N 400
#define NN   160000
#define EPSV 1e-4f
#define IND_BASE ((size_t)160400 * 64)

// ws offsets in floats
#define OFF_A     0         // 160000
#define OFF_P2    160000    // 12800
#define OFF_Q2    172800    // 12800
#define OFF_R     185600    // 25600
#define OFF_S     211200    // 25600
#define OFF_V4    236800    // 25600
#define OFF_AR    262400    // 25600  alpha_raw
#define OFF_NV    288000    // 400
#define OFF_DV    288400    // 400
#define OFF_CNT   288832    // 400 (int)
#define OFF_NNZ   289232    // 1 (int) total active edges (clamped to cap)
#define OFF_W34   289280    // 4096   W3 @ W_alpha
#define OFF_ARMAX 293376    // 400    per-row max |alpha_raw|
#define OFF_PART  293888    // EC*400*64 = 819200 partials
#define OFF_LIST  1113088   // up to 160000 (int)
#define OFF_WV    1273088   // cap*64

#define EC  32    // edge chunks
#define RPB 8     // rows per block
#define RT  (NV_N / RPB)   // 50 row tiles
#define SC  512   // sub-chunk staged in LDS

// kA: per-node precompute (blocks 0..399) + W34 (block 400, LDS-staged W3).
__global__ __launch_bounds__(256) void kA_pre(
    const float* __restrict__ NEE, const float* __restrict__ NFN,
    const float* __restrict__ W_n2e, const float* __restrict__ b_n2e,
    const float* __restrict__ W_n2e2, const float* __restrict__ b_n2e2,
    const float* __restrict__ W_ev1, const float* __restrict__ b_ev1,
    const float* __restrict__ W4,
    const float* __restrict__ W_ft1, const float* __restrict__ b_ft1,
    const float* __restrict__ W_ft2, const float* __restrict__ b_ft2,
    const float* __restrict__ W3, const float* __restrict__ W_alpha,
    float* __restrict__ ws)
{
    int b = blockIdx.x, t = threadIdx.x;
    if (b == NV_N) {
        // W34 = W3 @ W_alpha with W3 staged in LDS (no uniform-load latency chain)
        __shared__ float w3s[4096];
        for (int q = t; q < 4096; q += 256) w3s[q] = W3[q];
        __syncthreads();
        int lane = t & 63, w = t >> 6;
        for (int c = w; c < 64; c += 4) {
            float p = 0.f;
            #pragma unroll 8
            for (int k = 0; k < 64; ++k) p += w3s[c*64+k] * W_alpha[k*64+lane];
            ws[OFF_W34 + c*64 + lane] = p;
        }
        return;
    }
    __shared__ float xne[64], xnf[64], tP[64], tQ[64], hidN[32], hidF[32];
    int i = b;
    if (t < 64) { xne[t] = NEE[i*64+t]; xnf[t] = NFN[i*64+t]; }
    __syncthreads();
    if (t < 64) {
        int dd = t;
        float pv = b_n2e[dd], qv = 0.f, rv = b_n2e2[dd], sv = 0.f, v4 = 0.f;
        for (int k = 0; k < 64; ++k) {
            float xk = xne[k];
            pv += xk * W_n2e[k*64+dd];
            qv += xk * W_n2e[(64+k)*64+dd];
            rv += xk * W_n2e2[k*64+dd];
            sv += xk * W_n2e2[(64+k)*64+dd];
            v4 += fmaxf(xnf[k]-xk, 0.f) * W4[k*64+dd];
        }
        tP[dd] = pv; tQ[dd] = qv;
        ws[OFF_R  + i*64+dd] = rv;
        ws[OFF_S  + i*64+dd] = sv;
        ws[OFF_V4 + i*64+dd] = v4;
    } else if (t >= 64 && t < 96) {
        int dd = t - 64;
        float hn = b_ft1[dd], hf = b_ft1[dd];
        for (int k = 0; k < 64; ++k) { hn += xne[k]*W_ft1[k*32+dd]; hf += xnf[k]*W_ft1[k*32+dd]; }
        hidN[dd] = fmaxf(hn, 0.f); hidF[dd] = fmaxf(hf, 0.f);
    }
    __syncthreads();
    if (t < 32) {
        float p2 = b_ev1[t], q2 = 0.f;
        for (int c = 0; c < 64; ++c) { p2 += tP[c]*W_ev1[c*32+t]; q2 += tQ[c]*W_ev1[c*32+t]; }
        ws[OFF_P2 + i*32+t] = p2;
        ws[OFF_Q2 + i*32+t] = q2;
    }
    if (t == 96) {
        float num = b_ft2[0], den = b_ft2[0];
        for (int c = 0; c < 32; ++c) { num += hidN[c]*W_ft2[c]; den += hidF[c]*W_ft2[c]; }
        float dv = (den == 0.f) ? EPSV : den;
        ws[OFF_NV + i] = num / dv;
    }
}

// K2: A row + degree + count + indicator + owner-computes pred_edge. (unchanged)
__global__ __launch_bounds__(256) void k2_row(
    const float* __restrict__ NEE,
    const float* __restrict__ W_ev2, const float* __restrict__ b_ev2,
    const float* __restrict__ W_e2e, const float* __restrict__ b_e2e,
    float* __restrict__ ws, float* __restrict__ out)
{
    __shared__ float p2s[32], wev2[32], redf[256];
    __shared__ int rcnt[256];
    __shared__ unsigned char flag[NV_N];
    __shared__ int act[NV_N];
    __shared__ int s_cnt;
    int i = blockIdx.x, t = threadIdx.x;
    if (t < 32) { p2s[t] = ws[OFF_P2 + i*32+t]; wev2[t] = W_ev2[t]; }
    __syncthreads();
    float b2 = b_ev2[0];
    float s = 0.f; int cc = 0;
    for (int j = t; j < NV_N; j += 256) {
        const float4* q2row = (const float4*)&ws[OFF_Q2 + j*32];
        float v = b2;
        #pragma unroll
        for (int c4 = 0; c4 < 8; ++c4) {
            float4 q = q2row[c4];
            v += fmaxf(p2s[c4*4+0]+q.x, 0.f) * wev2[c4*4+0];
            v += fmaxf(p2s[c4*4+1]+q.y, 0.f) * wev2[c4*4+1];
            v += fmaxf(p2s[c4*4+2]+q.z, 0.f) * wev2[c4*4+2];
            v += fmaxf(p2s[c4*4+3]+q.w, 0.f) * wev2[c4*4+3];
        }
        float a = fmaxf(v, 0.f);
        ws[OFF_A + i*NV_N + j] = a;
        bool f = (a >= 1.0f);
        flag[j] = f ? 1 : 0;
        out[IND_BASE + (size_t)i*NV_N + j] = f ? 1.f : 0.f;
        s += a; cc += f ? 1 : 0;
    }
    redf[t] = s; rcnt[t] = cc;
    __syncthreads();
    for (int st = 128; st > 0; st >>= 1) {
        if (t < st) { redf[t] += redf[t+st]; rcnt[t] += rcnt[t+st]; }
        __syncthreads();
    }
    if (t == 0) {
        ws[OFF_DV + i] = rsqrtf(fmaxf(redf[0], EPSV));
        ((int*)ws)[OFF_CNT + i] = rcnt[0];
    }
    if (t < 64) {
        int base = 0;
        for (int ch = 0; ch < 7; ++ch) {
            int j = ch*64 + t;
            bool f = (j < NV_N) && (flag[j] != 0);
            unsigned long long m = __ballot(f);
            if (f) {
                int pre = __popcll(m & ((1ull << t) - 1ull));
                act[base + pre] = j;
            }
            base += __popcll(m);
        }
        if (t == 0) s_cnt = base;
    }
    __syncthreads();
    {
        const float4 z4 = make_float4(0.f, 0.f, 0.f, 0.f);
        float4* orow = (float4*)(out + (NV_N + (size_t)i*NV_N) * 64);
        for (int q = t; q < NV_N*16; q += 256) {
            if (!flag[q >> 4]) orow[q] = z4;
        }
    }
    int cnt = s_cnt, lane = t & 63, w = t >> 6;
    for (int k = w; k < cnt; k += 4) {
        int j = act[k];
        int e = i*NV_N + j;
        float emb = NEE[(size_t)(NV_N + e)*64 + lane];
        float v = b_e2e[lane] + ws[OFF_R + i*64 + lane] + ws[OFF_S + j*64 + lane];
        #pragma unroll
        for (int c = 0; c < 64; ++c) v += __shfl(emb, c) * W_e2e[c*64 + lane];
        out[(size_t)(NV_N + e)*64 + lane] = v;
    }
}

// K3: alpha chain + compaction + wv. R9 version + NNZ store by block 399.
__global__ __launch_bounds__(256) void k3_alpha_compact(
    const float* __restrict__ NEE,
    const float* __restrict__ b_alpha,
    const float* __restrict__ W_gamma, const float* __restrict__ b_gamma,
    float* __restrict__ ws, int cap)
{
    __shared__ float coef[NV_N];
    __shared__ float part[4][64];
    __shared__ float nmS[64];
    __shared__ int act[NV_N];
    __shared__ int red[256];
    __shared__ int s_off, s_cnt;
    int i = blockIdx.x, t = threadIdx.x, lane = t & 63, w = t >> 6;

    int os = 0;
    for (int r = t; r < i; r += 256) os += ((const int*)ws)[OFF_CNT + r];
    red[t] = os; __syncthreads();
    for (int st = 128; st > 0; st >>= 1) { if (t < st) red[t] += red[t+st]; __syncthreads(); }
    if (t == 0) s_off = red[0];

    for (int j = t; j < NV_N; j += 256)
        coef[j] = ws[OFF_A + i*NV_N + j] * ws[OFF_DV + j];
    __syncthreads();

    float acc = 0.f;
    #pragma unroll 4
    for (int j = w*100; j < w*100 + 100; ++j)
        acc += coef[j] * NEE[j*64 + lane];
    part[w][lane] = acc;
    __syncthreads();
    if (t < 64) nmS[t] = (part[0][t] + part[1][t] + part[2][t] + part[3][t]) * ws[OFF_DV + i];
    __syncthreads();

    {
        float p = 0.f;
        #pragma unroll
        for (int c = w*16; c < w*16 + 16; ++c)
            p += nmS[c] * ws[OFF_W34 + c*64 + lane];
        part[w][lane] = p;
    }
    __syncthreads();
    if (w == 0) {
        float ar = b_alpha[lane] + part[0][lane] + part[1][lane] + part[2][lane] + part[3][lane];
        ws[OFF_AR + i*64 + lane] = ar;
        float mx = fabsf(ar);
        #pragma unroll
        for (int off = 32; off > 0; off >>= 1) mx = fmaxf(mx, __shfl_xor(mx, off));
        if (lane == 0) ws[OFF_ARMAX + i] = mx;
    } else if (w == 1) {
        int base = 0;
        for (int ch = 0; ch < 7; ++ch) {
            int j = ch*64 + lane;
            float a = (j < NV_N) ? ws[OFF_A + i*NV_N + j] : 0.f;
            bool f = (a >= 1.0f);
            unsigned long long m = __ballot(f);
            if (f) {
                int pre = __popcll(m & ((1ull << lane) - 1ull));
                act[base + pre] = j;
                int slot = s_off + base + pre;
                if (slot < cap) ((int*)ws)[OFF_LIST + slot] = i*NV_N + j;
            }
            base += __popcll(m);
        }
        if (lane == 0) s_cnt = base;
    }
    __syncthreads();
    if (i == NV_N - 1 && t == 0) {
        int total = s_off + s_cnt;
        ((int*)ws)[OFF_NNZ] = (total > cap) ? cap : total;
    }

    int cnt = s_cnt;
    for (int k = w; k < cnt; k += 4) {
        int slot = s_off + k;
        if (slot >= cap) break;
        int e = i*NV_N + act[k];
        float emb = NEE[(size_t)(NV_N + e)*64 + lane];
        float g = b_gamma[lane];
        #pragma unroll
        for (int c = 0; c < 64; ++c) g += __shfl(emb, c) * W_gamma[c*64 + lane];
        float mx = g;
        #pragma unroll
        for (int off = 32; off > 0; off >>= 1) mx = fmaxf(mx, __shfl_xor(mx, off));
        float p = __expf(g - mx);
        float ssum = p;
        #pragma unroll
        for (int off = 32; off > 0; off >>= 1) ssum += __shfl_xor(ssum, off);
        ws[OFF_WV + (size_t)slot*64 + lane] = (p / ssum) * emb;
    }
}

// K4: tiled split-E partial GEMM. grid (EC, RT), block 256.
// Block (c, rt): rows [rt*8, rt*8+8) x edge-chunk c. WV read once per chunk,
// 8 FMAs per WV load. Writes PART[c][row][lane].
__global__ __launch_bounds__(256) void k4_partials(
    const float* __restrict__ A_ne,
    float* __restrict__ ws)
{
    __shared__ float av[RPB][SC];
    __shared__ int el[SC];
    int chunk = blockIdx.x, rt = blockIdx.y, t = threadIdx.x;
    int lane = t & 63, w = t >> 6;
    int nnz = ((const int*)ws)[OFF_NNZ];
    int CH = (nnz + EC - 1) / EC;
    int l0 = chunk * CH;
    int l1 = l0 + CH; if (l1 > nnz) l1 = nnz;
    int r0 = rt * RPB;
    float acc[RPB];
    #pragma unroll
    for (int r = 0; r < RPB; ++r) acc[r] = 0.f;
    for (int base = l0; base < l1; base += SC) {
        int m = l1 - base; if (m > SC) m = SC;
        __syncthreads();
        for (int l = t; l < m; l += 256) el[l] = ((const int*)ws)[OFF_LIST + base + l];
        __syncthreads();
        #pragma unroll
        for (int r = 0; r < RPB; ++r)
            for (int l = t; l < m; l += 256)
                av[r][l] = A_ne[(size_t)(r0 + r) * NN + el[l]];
        __syncthreads();
        for (int ll = w; ll < m; ll += 4) {
            float wvv = ws[OFF_WV + (size_t)(base + ll) * 64 + lane];
            #pragma unroll
            for (int r = 0; r < RPB; ++r) acc[r] = fmaf(av[r][ll], wvv, acc[r]);
        }
    }
    __syncthreads();
    float* red = &av[0][0];   // reuse as 4*8*64 scratch
    #pragma unroll
    for (int r = 0; r < RPB; ++r) red[(w*RPB + r)*64 + lane] = acc[r];
    __syncthreads();
    if (w == 0) {
        #pragma unroll
        for (int r = 0; r < RPB; ++r) {
            float sum = red[(0*RPB+r)*64+lane] + red[(1*RPB+r)*64+lane]
                      + red[(2*RPB+r)*64+lane] + red[(3*RPB+r)*64+lane];
            ws[OFF_PART + ((size_t)chunk*NV_N + (r0+r))*64 + lane] = sum;
        }
    }
}

// K5: reduce partials + final pred_node. grid 400, block 64.
__global__ __launch_bounds__(64) void k5_final(
    const float* __restrict__ ws,
    float* __restrict__ out)
{
    int i = blockIdx.x, lane = threadIdx.x;
    float mx = 0.f;
    for (int r = lane; r < NV_N; r += 64) mx = fmaxf(mx, ws[OFF_ARMAX + r]);
    #pragma unroll
    for (int off = 32; off > 0; off >>= 1) mx = fmaxf(mx, __shfl_xor(mx, off));
    float amax = fmaxf(mx, EPSV);
    float aggr = 0.f;
    #pragma unroll 8
    for (int c = 0; c < EC; ++c)
        aggr += ws[OFF_PART + ((size_t)c*NV_N + i)*64 + lane];
    float v = (ws[OFF_AR + i*64 + lane] / amax) * ws[OFF_NV + i] * ws[OFF_V4 + i*64 + lane];
    out[i*64 + lane] = v + aggr;
}

extern "C" void kernel_launch(void* const* d_in, const int* in_sizes, int n_in,
                              void* d_out, int out_size, void* d_ws, size_t ws_size,
                              hipStream_t stream) {
    const float* NEE     = (const float*)d_in[1];
    const float* NFN     = (const float*)d_in[2];
    const float* A_ne    = (const float*)d_in[3];
    const float* W_alpha = (const float*)d_in[5];
    const float* b_alpha = (const float*)d_in[6];
    const float* W_gamma = (const float*)d_in[7];
    const float* b_gamma = (const float*)d_in[8];
    const float* W_n2e   = (const float*)d_in[9];
    const float* b_n2e   = (const float*)d_in[10];
    const float* W_ev1   = (const float*)d_in[11];
    const float* b_ev1   = (const float*)d_in[12];
    const float* W_ev2   = (const float*)d_in[13];
    const float* b_ev2   = (const float*)d_in[14];
    const float* W_ft1   = (const float*)d_in[15];
    const float* b_ft1   = (const float*)d_in[16];
    const float* W_ft2   = (const float*)d_in[17];
    const float* b_ft2   = (const float*)d_in[18];
    const float* W3      = (const float*)d_in[19];
    const float* W4      = (const float*)d_in[20];
    const float* W_e2e   = (const float*)d_in[21];
    const float* b_e2e   = (const float*)d_in[22];
    const float* W_n2e2  = (const float*)d_in[23];
    const float* b_n2e2  = (const float*)d_in[24];
    float* out = (float*)d_out;
    float* ws  = (float*)d_ws;

    long long cap_ll = ((long long)(ws_size / 4) - OFF_WV) / 64;
    int cap = (cap_ll > NN) ? NN : (cap_ll < 0 ? 0 : (int)cap_ll);

    hipLaunchKernelGGL(kA_pre, dim3(NV_N + 1), dim3(256), 0, stream,
        NEE, NFN, W_n2e, b_n2e, W_n2e2, b_n2e2, W_ev1, b_ev1, W4,
        W_ft1, b_ft1, W_ft2, b_ft2, W3, W_alpha, ws);
    hipLaunchKernelGGL(k2_row, dim3(NV_N), dim3(256), 0, stream,
        NEE, W_ev2, b_ev2, W_e2e, b_e2e, ws, out);
    hipLaunchKernelGGL(k3_alpha_compact, dim3(NV_N), dim3(256), 0, stream,
        NEE, b_alpha, W_gamma, b_gamma, ws, cap);
    hipLaunchKernelGGL(k4_partials, dim3(EC, RT), dim3(256), 0, stream,
        A_ne, ws);
    hipLaunchKernelGGL(k5_final, dim3(NV_N), dim3(64), 0, stream,
        ws, out);
}

// Round 11
// 39.609 us; speedup vs baseline: 101.1139x; 1.4798x over previous
//
#include <hip/hip_runtime.h>

#define NV_N 400
#define NN   160000
#define EPSV 1e-4f
#define IND_BASE ((size_t)160400 * 64)

// ws offsets in floats
#define OFF_A     0         // 160000  A matrix (flat e = i*400+j)
#define OFF_P2    160000    // 12800
#define OFF_Q2    172800    // 12800
#define OFF_R     185600    // 25600
#define OFF_S     211200    // 25600
#define OFF_V4    236800    // 25600
#define OFF_AR    262400    // 25600  alpha_raw
#define OFF_NV    288000    // 400    norm_value
#define OFF_DV    288400    // 400    1/sqrt(deg)
#define OFF_CNT   288832    // 400 (int) per-row active count
#define OFF_ARMAX 289280    // 400    per-row max |alpha_raw| (replaces atomicMax)
#define OFF_LIST  289792    // up to 160000 (int) compact active-edge list
#define OFF_WV    449792    // cap*64 gamma-weighted embeddings

// kA: per-node precompute. grid 400, block 256.  (R6 kA minus GMAX init)
__global__ __launch_bounds__(256) void kA_pre(
    const float* __restrict__ NEE, const float* __restrict__ NFN,
    const float* __restrict__ W_n2e, const float* __restrict__ b_n2e,
    const float* __restrict__ W_n2e2, const float* __restrict__ b_n2e2,
    const float* __restrict__ W_ev1, const float* __restrict__ b_ev1,
    const float* __restrict__ W4,
    const float* __restrict__ W_ft1, const float* __restrict__ b_ft1,
    const float* __restrict__ W_ft2, const float* __restrict__ b_ft2,
    float* __restrict__ ws)
{
    __shared__ float xne[64], xnf[64], tP[64], tQ[64], hidN[32], hidF[32];
    int i = blockIdx.x, t = threadIdx.x;
    if (t < 64) { xne[t] = NEE[i*64+t]; xnf[t] = NFN[i*64+t]; }
    __syncthreads();
    if (t < 64) {
        int dd = t;
        float pv = b_n2e[dd], qv = 0.f, rv = b_n2e2[dd], sv = 0.f, v4 = 0.f;
        for (int k = 0; k < 64; ++k) {
            float xk = xne[k];
            pv += xk * W_n2e[k*64+dd];
            qv += xk * W_n2e[(64+k)*64+dd];
            rv += xk * W_n2e2[k*64+dd];
            sv += xk * W_n2e2[(64+k)*64+dd];
            v4 += fmaxf(xnf[k]-xk, 0.f) * W4[k*64+dd];
        }
        tP[dd] = pv; tQ[dd] = qv;
        ws[OFF_R  + i*64+dd] = rv;
        ws[OFF_S  + i*64+dd] = sv;
        ws[OFF_V4 + i*64+dd] = v4;
    } else if (t >= 64 && t < 96) {
        int dd = t - 64;
        float hn = b_ft1[dd], hf = b_ft1[dd];
        for (int k = 0; k < 64; ++k) { hn += xne[k]*W_ft1[k*32+dd]; hf += xnf[k]*W_ft1[k*32+dd]; }
        hidN[dd] = fmaxf(hn, 0.f); hidF[dd] = fmaxf(hf, 0.f);
    }
    __syncthreads();
    if (t < 32) {
        float p2 = b_ev1[t], q2 = 0.f;
        for (int c = 0; c < 64; ++c) { p2 += tP[c]*W_ev1[c*32+t]; q2 += tQ[c]*W_ev1[c*32+t]; }
        ws[OFF_P2 + i*32+t] = p2;
        ws[OFF_Q2 + i*32+t] = q2;
    }
    if (t == 96) {
        float num = b_ft2[0], den = b_ft2[0];
        for (int c = 0; c < 32; ++c) { num += hidN[c]*W_ft2[c]; den += hidF[c]*W_ft2[c]; }
        float dv = (den == 0.f) ? EPSV : den;
        ws[OFF_NV + i] = num / dv;
    }
}

// K2: A row + degree + count + indicator + owner-computes pred_edge.
// grid 400 (row i), block 256.  (R6 verbatim)
__global__ __launch_bounds__(256) void k2_row(
    const float* __restrict__ NEE,
    const float* __restrict__ W_ev2, const float* __restrict__ b_ev2,
    const float* __restrict__ W_e2e, const float* __restrict__ b_e2e,
    float* __restrict__ ws, float* __restrict__ out)
{
    __shared__ float p2s[32], wev2[32], redf[256];
    __shared__ int rcnt[256];
    __shared__ unsigned char flag[NV_N];
    __shared__ int act[NV_N];
    __shared__ int s_cnt;
    int i = blockIdx.x, t = threadIdx.x;
    if (t < 32) { p2s[t] = ws[OFF_P2 + i*32+t]; wev2[t] = W_ev2[t]; }
    __syncthreads();
    float b2 = b_ev2[0];
    float s = 0.f; int cc = 0;
    for (int j = t; j < NV_N; j += 256) {
        const float4* q2row = (const float4*)&ws[OFF_Q2 + j*32];
        float v = b2;
        #pragma unroll
        for (int c4 = 0; c4 < 8; ++c4) {
            float4 q = q2row[c4];
            v += fmaxf(p2s[c4*4+0]+q.x, 0.f) * wev2[c4*4+0];
            v += fmaxf(p2s[c4*4+1]+q.y, 0.f) * wev2[c4*4+1];
            v += fmaxf(p2s[c4*4+2]+q.z, 0.f) * wev2[c4*4+2];
            v += fmaxf(p2s[c4*4+3]+q.w, 0.f) * wev2[c4*4+3];
        }
        float a = fmaxf(v, 0.f);
        ws[OFF_A + i*NV_N + j] = a;
        bool f = (a >= 1.0f);
        flag[j] = f ? 1 : 0;
        out[IND_BASE + (size_t)i*NV_N + j] = f ? 1.f : 0.f;
        s += a; cc += f ? 1 : 0;
    }
    redf[t] = s; rcnt[t] = cc;
    __syncthreads();
    for (int st = 128; st > 0; st >>= 1) {
        if (t < st) { redf[t] += redf[t+st]; rcnt[t] += rcnt[t+st]; }
        __syncthreads();
    }
    if (t == 0) {
        ws[OFF_DV + i] = rsqrtf(fmaxf(redf[0], EPSV));
        ((int*)ws)[OFF_CNT + i] = rcnt[0];
    }
    if (t < 64) {
        int base = 0;
        for (int ch = 0; ch < 7; ++ch) {
            int j = ch*64 + t;
            bool f = (j < NV_N) && (flag[j] != 0);
            unsigned long long m = __ballot(f);
            if (f) {
                int pre = __popcll(m & ((1ull << t) - 1ull));
                act[base + pre] = j;
            }
            base += __popcll(m);
        }
        if (t == 0) s_cnt = base;
    }
    __syncthreads();
    {
        const float4 z4 = make_float4(0.f, 0.f, 0.f, 0.f);
        float4* orow = (float4*)(out + (NV_N + (size_t)i*NV_N) * 64);
        for (int q = t; q < NV_N*16; q += 256) {
            if (!flag[q >> 4]) orow[q] = z4;
        }
    }
    int cnt = s_cnt, lane = t & 63, w = t >> 6;
    for (int k = w; k < cnt; k += 4) {
        int j = act[k];
        int e = i*NV_N + j;
        float emb = NEE[(size_t)(NV_N + e)*64 + lane];
        float v = b_e2e[lane] + ws[OFF_R + i*64 + lane] + ws[OFF_S + j*64 + lane];
        #pragma unroll
        for (int c = 0; c < 64; ++c) v += __shfl(emb, c) * W_e2e[c*64 + lane];
        out[(size_t)(NV_N + e)*64 + lane] = v;
    }
}

// K3: alpha chain + global compaction + wv per active edge. grid 400, block 256.
// (R6 verbatim EXCEPT: atomicMax -> plain per-row ARMAX store)
__global__ __launch_bounds__(256) void k3_alpha_compact(
    const float* __restrict__ NEE,
    const float* __restrict__ W3,
    const float* __restrict__ W_alpha, const float* __restrict__ b_alpha,
    const float* __restrict__ W_gamma, const float* __restrict__ b_gamma,
    float* __restrict__ ws, int cap)
{
    __shared__ float part[4][64];
    __shared__ int red[256];
    __shared__ int s_off;
    int i = blockIdx.x, t = threadIdx.x, lane = t & 63, w = t >> 6;
    // offset = sum of counts[r] for r < i
    int os = 0;
    for (int r = t; r < i; r += 256) os += ((const int*)ws)[OFF_CNT + r];
    red[t] = os; __syncthreads();
    for (int st = 128; st > 0; st >>= 1) { if (t < st) red[t] += red[t+st]; __syncthreads(); }
    if (t == 0) s_off = red[0];
    // alpha partials: wave w covers j in [w*100, w*100+100)
    float acc = 0.f;
    for (int j = w*100; j < w*100 + 100; ++j) {
        float coef = ws[OFF_A + i*NV_N + j] * ws[OFF_DV + j];
        acc += coef * NEE[j*64 + lane];
    }
    part[w][lane] = acc;
    __syncthreads();   // also publishes s_off
    if (w == 0) {
        float nm = (part[0][lane] + part[1][lane] + part[2][lane] + part[3][lane]) * ws[OFF_DV + i];
        float mc = 0.f;
        #pragma unroll
        for (int c = 0; c < 64; ++c) mc += __shfl(nm, c) * W3[c*64 + lane];
        float ar = b_alpha[lane];
        #pragma unroll
        for (int c = 0; c < 64; ++c) ar += __shfl(mc, c) * W_alpha[c*64 + lane];
        ws[OFF_AR + i*64 + lane] = ar;
        float mx = fabsf(ar);
        #pragma unroll
        for (int off = 32; off > 0; off >>= 1) mx = fmaxf(mx, __shfl_xor(mx, off));
        if (lane == 0) ws[OFF_ARMAX + i] = mx;   // plain store, no contended atomic
    } else if (w == 1) {
        // ordered compaction of this row into the global list
        int base = 0;
        for (int ch = 0; ch < 7; ++ch) {
            int j = ch*64 + lane;
            float a = (j < NV_N) ? ws[OFF_A + i*NV_N + j] : 0.f;
            bool f = (a >= 1.0f);
            unsigned long long m = __ballot(f);
            if (f) {
                int pre = __popcll(m & ((1ull << lane) - 1ull));
                int slot = s_off + base + pre;
                if (slot < cap) ((int*)ws)[OFF_LIST + slot] = i*NV_N + j;
            }
            base += __popcll(m);
        }
    }
    __syncthreads();
    // wv for this row's actives: wave w takes k = w, w+4, ...
    int cnt = ((const int*)ws)[OFF_CNT + i];
    for (int k = w; k < cnt; k += 4) {
        int slot = s_off + k;
        if (slot >= cap) break;
        int e = ((const int*)ws)[OFF_LIST + slot];
        float emb = NEE[(size_t)(NV_N + e)*64 + lane];
        float g = b_gamma[lane];
        #pragma unroll
        for (int c = 0; c < 64; ++c) g += __shfl(emb, c) * W_gamma[c*64 + lane];
        float mx = g;
        #pragma unroll
        for (int off = 32; off > 0; off >>= 1) mx = fmaxf(mx, __shfl_xor(mx, off));
        float p = __expf(g - mx);
        float ssum = p;
        #pragma unroll
        for (int off = 32; off > 0; off >>= 1) ssum += __shfl_xor(ssum, off);
        ws[OFF_WV + (size_t)slot*64 + lane] = (p / ssum) * emb;
    }
}

// K4: gather-GEMM over compact list + ARMAX reduce + final node out.
// grid 400, block 256.  (R6 k4 + ARMAX max-reduce in the existing CNT scan)
#define LCHUNK 4096
__global__ __launch_bounds__(256) void k4_final(
    const float* __restrict__ A_ne,
    const float* __restrict__ ws, int cap,
    float* __restrict__ out)
{
    __shared__ float av[LCHUNK];
    __shared__ float part[4][64];
    __shared__ int red[256];
    __shared__ float redm[256];
    int i = blockIdx.x, t = threadIdx.x, lane = t & 63, w = t >> 6;
    int os = 0;
    float m0 = 0.f;
    for (int r = t; r < NV_N; r += 256) {
        os += ((const int*)ws)[OFF_CNT + r];
        m0 = fmaxf(m0, ws[OFF_ARMAX + r]);
    }
    red[t] = os; redm[t] = m0; __syncthreads();
    for (int st = 128; st > 0; st >>= 1) {
        if (t < st) { red[t] += red[t+st]; redm[t] = fmaxf(redm[t], redm[t+st]); }
        __syncthreads();
    }
    int nnz = red[0]; if (nnz > cap) nnz = cap;
    const float* Arow = A_ne + (size_t)i * NN;
    float acc = 0.f;
    for (int base = 0; base < nnz; base += LCHUNK) {
        int m = nnz - base; if (m > LCHUNK) m = LCHUNK;
        __syncthreads();
        for (int l = t; l < m; l += 256) {
            int e = ((const int*)ws)[OFF_LIST + base + l];
            av[l] = Arow[e];
        }
        __syncthreads();
        for (int l = w; l < m; l += 4)
            acc = fmaf(av[l], ws[OFF_WV + (size_t)(base + l)*64 + lane], acc);
    }
    part[w][lane] = acc;
    __syncthreads();
    if (w == 0) {
        float aggr = part[0][lane] + part[1][lane] + part[2][lane] + part[3][lane];
        float amax = fmaxf(redm[0], EPSV);
        float v = (ws[OFF_AR + i*64 + lane] / amax) * ws[OFF_NV + i] * ws[OFF_V4 + i*64 + lane];
        out[i*64 + lane] = v + aggr;
    }
}

extern "C" void kernel_launch(void* const* d_in, const int* in_sizes, int n_in,
                              void* d_out, int out_size, void* d_ws, size_t ws_size,
                              hipStream_t stream) {
    const float* NEE     = (const float*)d_in[1];
    const float* NFN     = (const float*)d_in[2];
    const float* A_ne    = (const float*)d_in[3];
    const float* W_alpha = (const float*)d_in[5];
    const float* b_alpha = (const float*)d_in[6];
    const float* W_gamma = (const float*)d_in[7];
    const float* b_gamma = (const float*)d_in[8];
    const float* W_n2e   = (const float*)d_in[9];
    const float* b_n2e   = (const float*)d_in[10];
    const float* W_ev1   = (const float*)d_in[11];
    const float* b_ev1   = (const float*)d_in[12];
    const float* W_ev2   = (const float*)d_in[13];
    const float* b_ev2   = (const float*)d_in[14];
    const float* W_ft1   = (const float*)d_in[15];
    const float* b_ft1   = (const float*)d_in[16];
    const float* W_ft2   = (const float*)d_in[17];
    const float* b_ft2   = (const float*)d_in[18];
    const float* W3      = (const float*)d_in[19];
    const float* W4      = (const float*)d_in[20];
    const float* W_e2e   = (const float*)d_in[21];
    const float* b_e2e   = (const float*)d_in[22];
    const float* W_n2e2  = (const float*)d_in[23];
    const float* b_n2e2  = (const float*)d_in[24];
    float* out = (float*)d_out;
    float* ws  = (float*)d_ws;

    long long cap_ll = ((long long)(ws_size / 4) - OFF_WV) / 64;
    int cap = (cap_ll > NN) ? NN : (cap_ll < 0 ? 0 : (int)cap_ll);

    hipLaunchKernelGGL(kA_pre, dim3(NV_N), dim3(256), 0, stream,
        NEE, NFN, W_n2e, b_n2e, W_n2e2, b_n2e2, W_ev1, b_ev1, W4,
        W_ft1, b_ft1, W_ft2, b_ft2, ws);
    hipLaunchKernelGGL(k2_row, dim3(NV_N), dim3(256), 0, stream,
        NEE, W_ev2, b_ev2, W_e2e, b_e2e, ws, out);
    hipLaunchKernelGGL(k3_alpha_compact, dim3(NV_N), dim3(256), 0, stream,
        NEE, W3, W_alpha, b_alpha, W_gamma, b_gamma, ws, cap);
    hipLaunchKernelGGL(k4_final, dim3(NV_N), dim3(256), 0, stream,
        A_ne, ws, cap, out);
}